// Round 9
// baseline (531.563 us; speedup 1.0000x reference)
//
#include <hip/hip_runtime.h>
#include <hip/hip_bf16.h>
#include <stdint.h>

#define IN_F 128
#define OUT_F 16
#define NEG_SLOPE 0.2f
#define SB_BITS 9               // super-bucket = 512 nodes (scatter granularity)
#define SB_NODES 512
#define NBS 196                 // ceil(100000/512)
#define CAP_SB 17408            // mean 16366, sigma ~127 -> +8 sigma
#define TILE_NODES 128          // agg output tile (quad of an SB)
#define LCAP 4608               // per-quad capacity (mean 4092, +8 sigma)
#define SC_E 4096               // edges per scatter block
#define W_LD (IN_F + 4)         // pad: 132%32==4 -> 2-way (free); 128 was 16-way
#define ACC_LD 17               // accS row stride: 16 would be 32-way bank conflict
#define SB_SPACING 200          // 200%8==0 -> all 4 quads of an SB on same XCD

// scatter LDS: hist/pref/gbase/rank (4*196*4=3136) + sortedP 16K + sortedB 4K
#define SMEM_BYTES (3136 + 16384 + 4096)

// ---------------------------------------------------------------------------
// Fused proj + scatter (independent work; one dispatch, overlapped HBM streams)
// ---------------------------------------------------------------------------
__global__ __launch_bounds__(256) void proj_scatter_kernel(
    const float* __restrict__ h, const float* __restrict__ W,
    const float* __restrict__ a_l, const float* __restrict__ a_r,
    const int* __restrict__ src, const int* __restrict__ dst,
    float* __restrict__ hW, float* __restrict__ el, float* __restrict__ er,
    int* __restrict__ cursor, uint32_t* __restrict__ payload,
    int N, int E, int scatBlocks) {
  __shared__ __align__(16) uint8_t smem[SMEM_BYTES];
  int t = threadIdx.x;

  if ((int)blockIdx.x < scatBlocks) {
    // ---------------- scatter branch ----------------
    int* hist = (int*)smem;          // NBS
    int* pref = hist + NBS;
    int* gbase = pref + NBS;
    int* rank = gbase + NBS;
    uint32_t* sortedP = (uint32_t*)(smem + 3136);
    uint8_t* sortedB = smem + 3136 + 16384;

    int start = blockIdx.x * SC_E;
    int end = min(E, start + SC_E);
    int cnt = end - start;

    if (t < NBS) { hist[t] = 0; rank[t] = 0; }
    __syncthreads();

    // hist pass: int4-vectorized dst scan
    const int4* dst4 = (const int4*)(dst + start);
    int n4 = cnt >> 2;               // SC_E%4==0 and E%4==0 -> exact
    for (int i = t; i < n4; i += 256) {
      int4 d = dst4[i];
      atomicAdd(&hist[d.x >> SB_BITS], 1);
      atomicAdd(&hist[d.y >> SB_BITS], 1);
      atomicAdd(&hist[d.z >> SB_BITS], 1);
      atomicAdd(&hist[d.w >> SB_BITS], 1);
    }
    for (int i = start + (n4 << 2) + t; i < end; i += 256)
      atomicAdd(&hist[dst[i] >> SB_BITS], 1);
    __syncthreads();

    if (t < NBS) {  // parallel O(n) exclusive prefix (was serial thread-0)
      int s = 0;
      for (int j = 0; j < t; ++j) s += hist[j];
      pref[t] = s;
      int c = hist[t];
      gbase[t] = c ? atomicAdd(&cursor[t * 16], c) : 0;  // cursor pre-zeroed
    }
    __syncthreads();

    // placement pass: int4-vectorized src+dst
    const int4* src4 = (const int4*)(src + start);
    for (int i = t; i < n4; i += 256) {
      int4 d = dst4[i];
      int4 s = src4[i];
#pragma unroll
      for (int j = 0; j < 4; ++j) {
        int dd = j == 0 ? d.x : j == 1 ? d.y : j == 2 ? d.z : d.w;
        int ss = j == 0 ? s.x : j == 1 ? s.y : j == 2 ? s.z : s.w;
        int b = dd >> SB_BITS;
        int r = atomicAdd(&rank[b], 1);
        int pos = pref[b] + r;
        sortedP[pos] = ((uint32_t)ss << SB_BITS) | (uint32_t)(dd & (SB_NODES - 1));
        sortedB[pos] = (uint8_t)b;
      }
    }
    for (int i = start + (n4 << 2) + t; i < end; i += 256) {
      int dd = dst[i];
      int b = dd >> SB_BITS;
      int r = atomicAdd(&rank[b], 1);
      int pos = pref[b] + r;
      sortedP[pos] = ((uint32_t)src[i] << SB_BITS) | (uint32_t)(dd & (SB_NODES - 1));
      sortedB[pos] = (uint8_t)b;
    }
    __syncthreads();

    for (int i = t; i < cnt; i += 256) {
      int b = sortedB[i];
      int ofs = gbase[b] + (i - pref[b]);
      if (ofs < CAP_SB) payload[(size_t)b * CAP_SB + ofs] = sortedP[i];
    }
  } else {
    // ---------------- projection branch ----------------
    float* Ws = (float*)smem;  // OUT_F * W_LD = 8448 B < SMEM_BYTES
    for (int i = t; i < OUT_F * IN_F; i += 256)
      Ws[(i >> 7) * W_LD + (i & (IN_F - 1))] = W[i];
    __syncthreads();

    int gid = ((int)blockIdx.x - scatBlocks) * 256 + t;
    int node = gid >> 4;
    int feat = gid & 15;
    if (node >= N) return;

    const float4* hrow = (const float4*)(h + (size_t)node * IN_F);
    const float4* wrow = (const float4*)(&Ws[feat * W_LD]);
    float acc = 0.f;
#pragma unroll
    for (int k = 0; k < IN_F / 4; ++k) {
      float4 hv = hrow[k];
      float4 wv = wrow[k];
      acc += hv.x * wv.x + hv.y * wv.y + hv.z * wv.z + hv.w * wv.w;
    }
    hW[node * OUT_F + feat] = acc;

    float vl = acc * a_l[feat];
    float vr = acc * a_r[feat];
#pragma unroll
    for (int off = 8; off; off >>= 1) {
      vl += __shfl_down(vl, off, 16);
      vr += __shfl_down(vr, off, 16);
    }
    if (feat == 0) {
      el[node] = vl;
      er[node] = vr;
    }
  }
}

// ---------------------------------------------------------------------------
// Sortless aggregate. Block = one 128-node quad of a super-bucket; XCD swizzle
// keeps all 4 quads of an SB on one XCD so the payload scan is L2-hot.
// Pass 1: single uint4 scan, ballot-compact kept edges into LDS (full-lane).
// Pass 2: one thread per edge -> 1 exp, 4x float4 hW gather, 16 LDS atomicAdds
// into stride-17 accumulator (order-free; replaces r8's counting sort + its
// 2nd global scan + hist/prefix/rank). Pass 3: normalize + coalesced store.
// ---------------------------------------------------------------------------
__global__ __launch_bounds__(512) void agg_kernel(
    const uint32_t* __restrict__ payload, const int* __restrict__ cursor,
    const float* __restrict__ hW, const float* __restrict__ el,
    const float* __restrict__ er, float* __restrict__ out, int N) {
  __shared__ uint32_t kept[LCAP];               // 18 KB
  __shared__ float accS[TILE_NODES * ACC_LD];   // 8.7 KB
  __shared__ float esumS[TILE_NODES];
  __shared__ int kcnt;

  int t = threadIdx.x;
  int sb = blockIdx.x % SB_SPACING;
  uint32_t quad = blockIdx.x / SB_SPACING;
  if (sb >= NBS) return;
  size_t base = (size_t)sb * CAP_SB;
  int cnt = min(cursor[sb * 16], CAP_SB);

  for (int i = t; i < TILE_NODES * ACC_LD; i += 512) accS[i] = 0.f;
  if (t < TILE_NODES) esumS[t] = 0.f;
  if (t == 0) kcnt = 0;
  __syncthreads();

  // pass 1: filter + ballot-compact (one global scan per quad)
  const uint4* pay4 = (const uint4*)(payload + base);  // CAP_SB%4==0
  int n4 = (cnt + 3) >> 2;
  int lane = t & 63;
  for (int i = t; i < n4; i += 512) {
    uint4 v = pay4[i];
    int i0 = i << 2;
#pragma unroll
    for (int j = 0; j < 4; ++j) {
      uint32_t p = j == 0 ? v.x : j == 1 ? v.y : j == 2 ? v.z : v.w;
      bool keep = (i0 + j < cnt) && (((p >> 7) & 3u) == quad);
      unsigned long long m = __ballot(keep);
      if (m) {
        int leader = (int)(__ffsll((long long)m) - 1);
        int bbase = 0;
        if (lane == leader) bbase = atomicAdd(&kcnt, (int)__popcll(m));
        bbase = __shfl(bbase, leader);
        if (keep)
          kept[bbase + (int)__popcll(m & ((1ull << lane) - 1))] = p;
      }
    }
  }
  __syncthreads();
  int K = kcnt;

  // pass 2: one thread per edge, full-lane active
  int node0 = sb * SB_NODES;
  for (int i = t; i < K; i += 512) {
    uint32_t p = kept[i];
    int s = (int)(p >> SB_BITS);
    int dl = (int)(p & (SB_NODES - 1));
    float x = el[s] + er[node0 + dl];
    x = x > 0.f ? x : NEG_SLOPE * x;
    float ex = __expf(x);
    int tl = dl & (TILE_NODES - 1);
    const float4* hw4 = (const float4*)(hW + (size_t)s * OUT_F);
    float4 h0 = hw4[0], h1 = hw4[1], h2 = hw4[2], h3 = hw4[3];
    float* arow = &accS[tl * ACC_LD];
    atomicAdd(&arow[0],  ex * h0.x);
    atomicAdd(&arow[1],  ex * h0.y);
    atomicAdd(&arow[2],  ex * h0.z);
    atomicAdd(&arow[3],  ex * h0.w);
    atomicAdd(&arow[4],  ex * h1.x);
    atomicAdd(&arow[5],  ex * h1.y);
    atomicAdd(&arow[6],  ex * h1.z);
    atomicAdd(&arow[7],  ex * h1.w);
    atomicAdd(&arow[8],  ex * h2.x);
    atomicAdd(&arow[9],  ex * h2.y);
    atomicAdd(&arow[10], ex * h2.z);
    atomicAdd(&arow[11], ex * h2.w);
    atomicAdd(&arow[12], ex * h3.x);
    atomicAdd(&arow[13], ex * h3.y);
    atomicAdd(&arow[14], ex * h3.z);
    atomicAdd(&arow[15], ex * h3.w);
    atomicAdd(&esumS[tl], ex);
  }
  __syncthreads();

  // pass 3: normalize + coalesced store
  int outBase = sb * SB_NODES + (int)quad * TILE_NODES;
  int nlocal = min(TILE_NODES, N - outBase);
  for (int i = t; i < nlocal * OUT_F; i += 512) {
    int tl = i >> 4;
    out[(size_t)outBase * OUT_F + i] =
        accS[tl * ACC_LD + (i & 15)] / fmaxf(esumS[tl], 1e-16f);
  }
}

extern "C" void kernel_launch(void* const* d_in, const int* in_sizes, int n_in,
                              void* d_out, int out_size, void* d_ws, size_t ws_size,
                              hipStream_t stream) {
  const float* h   = (const float*)d_in[0];
  const int*   src = (const int*)d_in[1];
  const int*   dst = (const int*)d_in[2];
  const float* W   = (const float*)d_in[3];
  const float* a_l = (const float*)d_in[4];
  const float* a_r = (const float*)d_in[5];
  float* out = (float*)d_out;

  const int N = in_sizes[0] / IN_F;
  const int E = in_sizes[1];
  const int scatBlocks = (E + SC_E - 1) / SC_E;      // 782
  const int projBlocks = (N * OUT_F + 255) / 256;    // 6250

  // ws: hW | el | er | cursor | payload (payload 16B-aligned by layout)
  float* ws = (float*)d_ws;
  float* hW = ws;                                  // N*16
  float* el = hW + (size_t)N * OUT_F;              // N
  float* er = el + N;                              // N
  int* cursor = (int*)(er + N);                    // NBS*16 (line-strided)
  uint32_t* payload = (uint32_t*)(cursor + (size_t)NBS * 16);  // NBS*CAP_SB

  hipMemsetAsync(cursor, 0, (size_t)NBS * 16 * sizeof(int), stream);

  proj_scatter_kernel<<<scatBlocks + projBlocks, 256, 0, stream>>>(
      h, W, a_l, a_r, src, dst, hW, el, er, cursor, payload, N, E, scatBlocks);

  agg_kernel<<<SB_SPACING * 4, 512, 0, stream>>>(payload, cursor, hW, el, er,
                                                 out, N);
}

// Round 10
// 217.685 us; speedup vs baseline: 2.4419x; 2.4419x over previous
//
#include <hip/hip_runtime.h>
#include <hip/hip_bf16.h>
#include <stdint.h>

#define IN_F 128
#define OUT_F 16
#define NEG_SLOPE 0.2f
#define SB_BITS 9               // super-bucket = 512 nodes (scatter granularity)
#define SB_NODES 512
#define NBS 196                 // ceil(100000/512)
#define CAP_SB 17408            // mean 16366, sigma ~127 -> +8 sigma
#define TILE_NODES 128          // agg output tile (quad of an SB)
#define LCAP 4608               // per-quad capacity (mean 4092, +8 sigma)
#define SC_E 4096               // edges per scatter block
#define W_LD (IN_F + 4)         // pad: 132%32==4 -> 2-way (free); 128 was 16-way
#define SB_SPACING 200          // 200%8==0 -> all 4 quads of an SB on same XCD

// scatter LDS: hist/pref/gbase/rank (4*196*4=3136) + sortedP 16K + sortedB 4K
#define SMEM_BYTES (3136 + 16384 + 4096)

// ---------------------------------------------------------------------------
// Fused proj + scatter (independent work; one dispatch, overlapped HBM streams)
// ---------------------------------------------------------------------------
__global__ __launch_bounds__(256) void proj_scatter_kernel(
    const float* __restrict__ h, const float* __restrict__ W,
    const float* __restrict__ a_l, const float* __restrict__ a_r,
    const int* __restrict__ src, const int* __restrict__ dst,
    float* __restrict__ hW, float* __restrict__ el, float* __restrict__ er,
    int* __restrict__ cursor, uint32_t* __restrict__ payload,
    int N, int E, int scatBlocks) {
  __shared__ __align__(16) uint8_t smem[SMEM_BYTES];
  int t = threadIdx.x;

  if ((int)blockIdx.x < scatBlocks) {
    // ---------------- scatter branch ----------------
    int* hist = (int*)smem;          // NBS
    int* pref = hist + NBS;
    int* gbase = pref + NBS;
    int* rank = gbase + NBS;
    uint32_t* sortedP = (uint32_t*)(smem + 3136);
    uint8_t* sortedB = smem + 3136 + 16384;

    int start = blockIdx.x * SC_E;
    int end = min(E, start + SC_E);
    int cnt = end - start;

    if (t < NBS) { hist[t] = 0; rank[t] = 0; }
    __syncthreads();

    // hist pass: int4-vectorized dst scan
    const int4* dst4 = (const int4*)(dst + start);
    int n4 = cnt >> 2;
    for (int i = t; i < n4; i += 256) {
      int4 d = dst4[i];
      atomicAdd(&hist[d.x >> SB_BITS], 1);
      atomicAdd(&hist[d.y >> SB_BITS], 1);
      atomicAdd(&hist[d.z >> SB_BITS], 1);
      atomicAdd(&hist[d.w >> SB_BITS], 1);
    }
    for (int i = start + (n4 << 2) + t; i < end; i += 256)
      atomicAdd(&hist[dst[i] >> SB_BITS], 1);
    __syncthreads();

    if (t < NBS) {  // parallel O(n) exclusive prefix
      int s = 0;
      for (int j = 0; j < t; ++j) s += hist[j];
      pref[t] = s;
      int c = hist[t];
      gbase[t] = c ? atomicAdd(&cursor[t * 16], c) : 0;  // cursor pre-zeroed
    }
    __syncthreads();

    // placement pass: int4-vectorized src+dst
    const int4* src4 = (const int4*)(src + start);
    for (int i = t; i < n4; i += 256) {
      int4 d = dst4[i];
      int4 s = src4[i];
#pragma unroll
      for (int j = 0; j < 4; ++j) {
        int dd = j == 0 ? d.x : j == 1 ? d.y : j == 2 ? d.z : d.w;
        int ss = j == 0 ? s.x : j == 1 ? s.y : j == 2 ? s.z : s.w;
        int b = dd >> SB_BITS;
        int r = atomicAdd(&rank[b], 1);
        int pos = pref[b] + r;
        sortedP[pos] = ((uint32_t)ss << SB_BITS) | (uint32_t)(dd & (SB_NODES - 1));
        sortedB[pos] = (uint8_t)b;
      }
    }
    for (int i = start + (n4 << 2) + t; i < end; i += 256) {
      int dd = dst[i];
      int b = dd >> SB_BITS;
      int r = atomicAdd(&rank[b], 1);
      int pos = pref[b] + r;
      sortedP[pos] = ((uint32_t)src[i] << SB_BITS) | (uint32_t)(dd & (SB_NODES - 1));
      sortedB[pos] = (uint8_t)b;
    }
    __syncthreads();

    for (int i = t; i < cnt; i += 256) {
      int b = sortedB[i];
      int ofs = gbase[b] + (i - pref[b]);
      if (ofs < CAP_SB) payload[(size_t)b * CAP_SB + ofs] = sortedP[i];
    }
  } else {
    // ---------------- projection branch ----------------
    float* Ws = (float*)smem;  // OUT_F * W_LD = 8448 B < SMEM_BYTES
    for (int i = t; i < OUT_F * IN_F; i += 256)
      Ws[(i >> 7) * W_LD + (i & (IN_F - 1))] = W[i];
    __syncthreads();

    int gid = ((int)blockIdx.x - scatBlocks) * 256 + t;
    int node = gid >> 4;
    int feat = gid & 15;
    if (node >= N) return;

    const float4* hrow = (const float4*)(h + (size_t)node * IN_F);
    const float4* wrow = (const float4*)(&Ws[feat * W_LD]);
    float acc = 0.f;
#pragma unroll
    for (int k = 0; k < IN_F / 4; ++k) {
      float4 hv = hrow[k];
      float4 wv = wrow[k];
      acc += hv.x * wv.x + hv.y * wv.y + hv.z * wv.z + hv.w * wv.w;
    }
    hW[node * OUT_F + feat] = acc;

    float vl = acc * a_l[feat];
    float vr = acc * a_r[feat];
#pragma unroll
    for (int off = 8; off; off >>= 1) {
      vl += __shfl_down(vl, off, 16);
      vr += __shfl_down(vr, off, 16);
    }
    if (feat == 0) {
      el[node] = vl;
      er[node] = vr;
    }
  }
}

// ---------------------------------------------------------------------------
// Fused sort+aggregate (MEASURED-GOOD r8 structure; r9's sortless variant was
// 6x slower — the counting sort is what makes the CSR loop's hW access
// 16-lanes-per-line coalesced). blockIdx = quad*SB_SPACING + sb keeps all 4
// quads of an SB on one XCD -> payload scans L2-hot. uint4 scans; exp once
// per edge into exS[]; 16-lane-group register CSR aggregation + normalize.
// ---------------------------------------------------------------------------
__global__ __launch_bounds__(512) void agg_kernel(
    const uint32_t* __restrict__ payload, const int* __restrict__ cursor,
    const float* __restrict__ hW, const float* __restrict__ el,
    const float* __restrict__ er, float* __restrict__ out, int N) {
  __shared__ uint32_t sorted[LCAP];  // 18 KB
  __shared__ float exS[LCAP];        // 18 KB
  __shared__ int hist[TILE_NODES];
  __shared__ int pref[TILE_NODES];
  __shared__ int rank[TILE_NODES];

  int t = threadIdx.x;
  int sb = blockIdx.x % SB_SPACING;
  int quad = blockIdx.x / SB_SPACING;
  if (sb >= NBS) return;
  size_t base = (size_t)sb * CAP_SB;
  int cnt = min(cursor[sb * 16], CAP_SB);

  if (t < TILE_NODES) { hist[t] = 0; rank[t] = 0; }
  __syncthreads();

  const uint4* pay4 = (const uint4*)(payload + base);  // CAP_SB%4==0
  int n4 = (cnt + 3) >> 2;
  for (int i = t; i < n4; i += 512) {
    uint4 v = pay4[i];
    int i0 = i << 2;
    if (i0 + 0 < cnt && (int)((v.x >> 7) & 3) == quad) atomicAdd(&hist[v.x & (TILE_NODES - 1)], 1);
    if (i0 + 1 < cnt && (int)((v.y >> 7) & 3) == quad) atomicAdd(&hist[v.y & (TILE_NODES - 1)], 1);
    if (i0 + 2 < cnt && (int)((v.z >> 7) & 3) == quad) atomicAdd(&hist[v.z & (TILE_NODES - 1)], 1);
    if (i0 + 3 < cnt && (int)((v.w >> 7) & 3) == quad) atomicAdd(&hist[v.w & (TILE_NODES - 1)], 1);
  }
  __syncthreads();

  if (t < TILE_NODES) {  // 128-thread O(n) prefix
    int s = 0;
    for (int j = 0; j < t; ++j) s += hist[j];
    pref[t] = s;
  }
  __syncthreads();

  for (int i = t; i < n4; i += 512) {  // re-read (L2-hot) and place
    uint4 v = pay4[i];
    int i0 = i << 2;
#pragma unroll
    for (int j = 0; j < 4; ++j) {
      uint32_t p = j == 0 ? v.x : j == 1 ? v.y : j == 2 ? v.z : v.w;
      if (i0 + j < cnt && (int)((p >> 7) & 3) == quad) {
        int dl = (int)(p & (TILE_NODES - 1));
        int r = atomicAdd(&rank[dl], 1);
        int pos = pref[dl] + r;
        if (pos < LCAP) sorted[pos] = p;
      }
    }
  }
  __syncthreads();

  int node0 = sb * SB_NODES + quad * TILE_NODES;
  int kept = pref[TILE_NODES - 1] + hist[TILE_NODES - 1];
  for (int i = t; i < kept; i += 512) {  // ex computed ONCE per edge
    uint32_t p = sorted[i];
    int s = (int)(p >> SB_BITS);
    float x = el[s] + er[node0 + (int)(p & (TILE_NODES - 1))];
    x = x > 0.f ? x : NEG_SLOPE * x;
    exS[i] = __expf(x);
  }
  __syncthreads();

  int g = t >> 4;  // 32 groups of 16 lanes
  int f = t & 15;
  for (int dl = g; dl < TILE_NODES; dl += 32) {
    int node = node0 + dl;
    if (node >= N) break;
    int k = pref[dl];
    int kend = k + hist[dl];
    float acc = 0.f;
    float es = 0.f;
#pragma unroll 4
    for (; k < kend; ++k) {
      float ex = exS[k];
      acc += ex * hW[(int)(sorted[k] >> SB_BITS) * OUT_F + f];
      es += ex;
    }
    out[(size_t)node * OUT_F + f] = acc / fmaxf(es, 1e-16f);
  }
}

extern "C" void kernel_launch(void* const* d_in, const int* in_sizes, int n_in,
                              void* d_out, int out_size, void* d_ws, size_t ws_size,
                              hipStream_t stream) {
  const float* h   = (const float*)d_in[0];
  const int*   src = (const int*)d_in[1];
  const int*   dst = (const int*)d_in[2];
  const float* W   = (const float*)d_in[3];
  const float* a_l = (const float*)d_in[4];
  const float* a_r = (const float*)d_in[5];
  float* out = (float*)d_out;

  const int N = in_sizes[0] / IN_F;
  const int E = in_sizes[1];
  const int scatBlocks = (E + SC_E - 1) / SC_E;      // 782
  const int projBlocks = (N * OUT_F + 255) / 256;    // 6250

  // ws: hW | el | er | cursor | payload (payload 16B-aligned by layout)
  float* ws = (float*)d_ws;
  float* hW = ws;                                  // N*16
  float* el = hW + (size_t)N * OUT_F;              // N
  float* er = el + N;                              // N
  int* cursor = (int*)(er + N);                    // NBS*16 (line-strided)
  uint32_t* payload = (uint32_t*)(cursor + (size_t)NBS * 16);  // NBS*CAP_SB

  hipMemsetAsync(cursor, 0, (size_t)NBS * 16 * sizeof(int), stream);

  proj_scatter_kernel<<<scatBlocks + projBlocks, 256, 0, stream>>>(
      h, W, a_l, a_r, src, dst, hW, el, er, cursor, payload, N, E, scatBlocks);

  agg_kernel<<<SB_SPACING * 4, 512, 0, stream>>>(payload, cursor, hW, el, er,
                                                 out, N);
}

// Round 11
// 215.717 us; speedup vs baseline: 2.4642x; 1.0091x over previous
//
#include <hip/hip_runtime.h>
#include <hip/hip_bf16.h>
#include <stdint.h>

#define IN_F 128
#define OUT_F 16
#define NEG_SLOPE 0.2f
#define SB_BITS 9               // super-bucket = 512 nodes (scatter granularity)
#define SB_NODES 512
#define NBS 196                 // ceil(100000/512)
#define CAP_SB 17408            // mean 16366, sigma ~127 -> +8 sigma
#define TILE_NODES 128          // agg output tile (quad of an SB)
#define LCAP 4608               // per-quad capacity (mean 4092, +8 sigma)
#define SC_E 8192               // edges per scatter block (r11: 2x for longer runs)
#define W_LD (IN_F + 4)         // pad: 132%32==4 -> 2-way (free); 128 was 16-way
#define SB_SPACING 200          // 200%8==0 -> all 4 quads of an SB on same XCD

// scatter LDS: hist/pref/gbase/rank (4*196*4=3136) + sortedP 32K (no sortedB)
#define SMEM_BYTES (3136 + SC_E * 4)

// ---------------------------------------------------------------------------
// Fused proj + scatter (independent work; one dispatch, overlapped HBM streams)
// ---------------------------------------------------------------------------
__global__ __launch_bounds__(256) void proj_scatter_kernel(
    const float* __restrict__ h, const float* __restrict__ W,
    const float* __restrict__ a_l, const float* __restrict__ a_r,
    const int* __restrict__ src, const int* __restrict__ dst,
    float* __restrict__ hW, float* __restrict__ el, float* __restrict__ er,
    int* __restrict__ cursor, uint32_t* __restrict__ payload,
    int N, int E, int scatBlocks) {
  __shared__ __align__(16) uint8_t smem[SMEM_BYTES];
  int t = threadIdx.x;

  if ((int)blockIdx.x < scatBlocks) {
    // ---------------- scatter branch ----------------
    int* hist = (int*)smem;          // NBS
    int* pref = hist + NBS;
    int* gbase = pref + NBS;
    int* rank = gbase + NBS;
    uint32_t* sortedP = (uint32_t*)(smem + 3136);  // SC_E

    int start = blockIdx.x * SC_E;
    int end = min(E, start + SC_E);
    int cnt = end - start;

    if (t < NBS) { hist[t] = 0; rank[t] = 0; }
    __syncthreads();

    // hist pass: int4-vectorized dst scan
    const int4* dst4 = (const int4*)(dst + start);
    int n4 = cnt >> 2;
    for (int i = t; i < n4; i += 256) {
      int4 d = dst4[i];
      atomicAdd(&hist[d.x >> SB_BITS], 1);
      atomicAdd(&hist[d.y >> SB_BITS], 1);
      atomicAdd(&hist[d.z >> SB_BITS], 1);
      atomicAdd(&hist[d.w >> SB_BITS], 1);
    }
    for (int i = start + (n4 << 2) + t; i < end; i += 256)
      atomicAdd(&hist[dst[i] >> SB_BITS], 1);
    __syncthreads();

    if (t < NBS) {  // parallel O(n) exclusive prefix + range reservation
      int s = 0;
      for (int j = 0; j < t; ++j) s += hist[j];
      pref[t] = s;
      int c = hist[t];
      gbase[t] = c ? atomicAdd(&cursor[t * 16], c) : 0;  // cursor pre-zeroed
    }
    __syncthreads();

    // placement pass: int4-vectorized src+dst
    const int4* src4 = (const int4*)(src + start);
    for (int i = t; i < n4; i += 256) {
      int4 d = dst4[i];
      int4 s = src4[i];
#pragma unroll
      for (int j = 0; j < 4; ++j) {
        int dd = j == 0 ? d.x : j == 1 ? d.y : j == 2 ? d.z : d.w;
        int ss = j == 0 ? s.x : j == 1 ? s.y : j == 2 ? s.z : s.w;
        int b = dd >> SB_BITS;
        int r = atomicAdd(&rank[b], 1);
        sortedP[pref[b] + r] =
            ((uint32_t)ss << SB_BITS) | (uint32_t)(dd & (SB_NODES - 1));
      }
    }
    for (int i = start + (n4 << 2) + t; i < end; i += 256) {
      int dd = dst[i];
      int b = dd >> SB_BITS;
      int r = atomicAdd(&rank[b], 1);
      sortedP[pref[b] + r] =
          ((uint32_t)src[i] << SB_BITS) | (uint32_t)(dd & (SB_NODES - 1));
    }
    __syncthreads();

    // write-out: per-bucket run copy (wave per bucket; no per-edge b lookup)
    int wv = t >> 6, ln = t & 63;
    for (int b = wv; b < NBS; b += 4) {
      int c = hist[b];
      int p0 = pref[b];
      size_t g0 = (size_t)b * CAP_SB + gbase[b];
      for (int j = ln; j < c; j += 64)
        if (gbase[b] + j < CAP_SB) payload[g0 + j] = sortedP[p0 + j];
    }
  } else {
    // ---------------- projection branch ----------------
    float* Ws = (float*)smem;  // OUT_F * W_LD = 8448 B < SMEM_BYTES
    for (int i = t; i < OUT_F * IN_F; i += 256)
      Ws[(i >> 7) * W_LD + (i & (IN_F - 1))] = W[i];
    __syncthreads();

    int gid = ((int)blockIdx.x - scatBlocks) * 256 + t;
    int node = gid >> 4;
    int feat = gid & 15;
    if (node >= N) return;

    const float4* hrow = (const float4*)(h + (size_t)node * IN_F);
    const float4* wrow = (const float4*)(&Ws[feat * W_LD]);
    float acc = 0.f;
#pragma unroll
    for (int k = 0; k < IN_F / 4; ++k) {
      float4 hv = hrow[k];
      float4 wv = wrow[k];
      acc += hv.x * wv.x + hv.y * wv.y + hv.z * wv.z + hv.w * wv.w;
    }
    hW[node * OUT_F + feat] = acc;

    float vl = acc * a_l[feat];
    float vr = acc * a_r[feat];
#pragma unroll
    for (int off = 8; off; off >>= 1) {
      vl += __shfl_down(vl, off, 16);
      vr += __shfl_down(vr, off, 16);
    }
    if (feat == 0) {
      el[node] = vl;
      er[node] = vr;
    }
  }
}

// ---------------------------------------------------------------------------
// Fused sort+aggregate (r8 measured-good structure; r9's sortless variant was
// 6x slower). XCD swizzle keeps all 4 quads of an SB on one XCD -> payload
// scans L2-hot. After the LDS counting sort + per-edge exp, the CSR loop is
// now ONE WAVE PER DST ROW with lane=(e in 0..3, f in 0..15): 4 independent
// hW line-gathers per instruction (r10 had 1 per 16-lane group -> latency-
// bound at 4 lines in flight; this gives 16 with unroll 4). Cross-e reduce =
// 2 shuffles.
// ---------------------------------------------------------------------------
__global__ __launch_bounds__(512) void agg_kernel(
    const uint32_t* __restrict__ payload, const int* __restrict__ cursor,
    const float* __restrict__ hW, const float* __restrict__ el,
    const float* __restrict__ er, float* __restrict__ out, int N) {
  __shared__ uint32_t sorted[LCAP];  // 18 KB
  __shared__ float exS[LCAP];        // 18 KB
  __shared__ int hist[TILE_NODES];
  __shared__ int pref[TILE_NODES];
  __shared__ int rank[TILE_NODES];

  int t = threadIdx.x;
  int sb = blockIdx.x % SB_SPACING;
  int quad = blockIdx.x / SB_SPACING;
  if (sb >= NBS) return;
  size_t base = (size_t)sb * CAP_SB;
  int cnt = min(cursor[sb * 16], CAP_SB);

  if (t < TILE_NODES) { hist[t] = 0; rank[t] = 0; }
  __syncthreads();

  const uint4* pay4 = (const uint4*)(payload + base);  // CAP_SB%4==0
  int n4 = (cnt + 3) >> 2;
  for (int i = t; i < n4; i += 512) {
    uint4 v = pay4[i];
    int i0 = i << 2;
    if (i0 + 0 < cnt && (int)((v.x >> 7) & 3) == quad) atomicAdd(&hist[v.x & (TILE_NODES - 1)], 1);
    if (i0 + 1 < cnt && (int)((v.y >> 7) & 3) == quad) atomicAdd(&hist[v.y & (TILE_NODES - 1)], 1);
    if (i0 + 2 < cnt && (int)((v.z >> 7) & 3) == quad) atomicAdd(&hist[v.z & (TILE_NODES - 1)], 1);
    if (i0 + 3 < cnt && (int)((v.w >> 7) & 3) == quad) atomicAdd(&hist[v.w & (TILE_NODES - 1)], 1);
  }
  __syncthreads();

  if (t < TILE_NODES) {  // 128-thread O(n) prefix
    int s = 0;
    for (int j = 0; j < t; ++j) s += hist[j];
    pref[t] = s;
  }
  __syncthreads();

  for (int i = t; i < n4; i += 512) {  // re-read (L2-hot) and place
    uint4 v = pay4[i];
    int i0 = i << 2;
#pragma unroll
    for (int j = 0; j < 4; ++j) {
      uint32_t p = j == 0 ? v.x : j == 1 ? v.y : j == 2 ? v.z : v.w;
      if (i0 + j < cnt && (int)((p >> 7) & 3) == quad) {
        int dl = (int)(p & (TILE_NODES - 1));
        int r = atomicAdd(&rank[dl], 1);
        int pos = pref[dl] + r;
        if (pos < LCAP) sorted[pos] = p;
      }
    }
  }
  __syncthreads();

  int node0 = sb * SB_NODES + quad * TILE_NODES;
  int kept = pref[TILE_NODES - 1] + hist[TILE_NODES - 1];
  for (int i = t; i < kept; i += 512) {  // ex computed ONCE per edge
    uint32_t p = sorted[i];
    int s = (int)(p >> SB_BITS);
    float x = el[s] + er[node0 + (int)(p & (TILE_NODES - 1))];
    x = x > 0.f ? x : NEG_SLOPE * x;
    exS[i] = __expf(x);
  }
  __syncthreads();

  // CSR aggregate: one wave per dst row; lane = (e, f); 4 edges/instr.
  int wv = t >> 6;       // 8 waves
  int lane = t & 63;
  int e = lane >> 4;     // 0..3
  int f = lane & 15;
  for (int dl = wv; dl < TILE_NODES; dl += 8) {
    int node = node0 + dl;
    if (node >= N) break;
    int k0 = pref[dl];
    int kend = k0 + hist[dl];
    float acc = 0.f;
    float es = 0.f;
#pragma unroll 4
    for (int k = k0; k < kend; k += 4) {
      int kk = k + e;
      float ex = 0.f;
      int s = 0;
      if (kk < kend) {
        ex = exS[kk];
        s = (int)(sorted[kk] >> SB_BITS);
      }
      acc += ex * hW[s * OUT_F + f];  // masked lanes: ex=0 contributes 0
      es += ex;
    }
    acc += __shfl_down(acc, 32);
    acc += __shfl_down(acc, 16);
    es += __shfl_down(es, 32);
    es += __shfl_down(es, 16);
    if (lane < 16)
      out[(size_t)node * OUT_F + f] = acc / fmaxf(es, 1e-16f);
  }
}

extern "C" void kernel_launch(void* const* d_in, const int* in_sizes, int n_in,
                              void* d_out, int out_size, void* d_ws, size_t ws_size,
                              hipStream_t stream) {
  const float* h   = (const float*)d_in[0];
  const int*   src = (const int*)d_in[1];
  const int*   dst = (const int*)d_in[2];
  const float* W   = (const float*)d_in[3];
  const float* a_l = (const float*)d_in[4];
  const float* a_r = (const float*)d_in[5];
  float* out = (float*)d_out;

  const int N = in_sizes[0] / IN_F;
  const int E = in_sizes[1];
  const int scatBlocks = (E + SC_E - 1) / SC_E;      // 391
  const int projBlocks = (N * OUT_F + 255) / 256;    // 6250

  // ws: hW | el | er | cursor | payload (payload 16B-aligned by layout)
  float* ws = (float*)d_ws;
  float* hW = ws;                                  // N*16
  float* el = hW + (size_t)N * OUT_F;              // N
  float* er = el + N;                              // N
  int* cursor = (int*)(er + N);                    // NBS*16 (line-strided)
  uint32_t* payload = (uint32_t*)(cursor + (size_t)NBS * 16);  // NBS*CAP_SB

  hipMemsetAsync(cursor, 0, (size_t)NBS * 16 * sizeof(int), stream);

  proj_scatter_kernel<<<scatBlocks + projBlocks, 256, 0, stream>>>(
      h, W, a_l, a_r, src, dst, hW, el, er, cursor, payload, N, E, scatBlocks);

  agg_kernel<<<SB_SPACING * 4, 512, 0, stream>>>(payload, cursor, hW, el, er,
                                                 out, N);
}

// Round 12
// 196.971 us; speedup vs baseline: 2.6987x; 1.0952x over previous
//
#include <hip/hip_runtime.h>
#include <hip/hip_bf16.h>
#include <stdint.h>

#define IN_F 128
#define OUT_F 16
#define NEG_SLOPE 0.2f
#define SB_BITS 9               // super-bucket = 512 nodes (scatter granularity)
#define SB_NODES 512
#define NBS 196                 // ceil(100000/512)
#define CAP_SB 17408            // mean 16366, sigma ~127 -> +8 sigma
#define TILE_NODES 128          // agg output tile (quad of an SB)
#define LCAP 4608               // per-quad capacity (mean 4092, +8 sigma)
#define SC_E 8192               // edges per scatter block
#define W_LD (IN_F + 4)         // pad: 132%32==4 -> 2-way (free); 128 was 16-way
#define SB_SPACING 200          // 200%8==0 -> all 4 quads of an SB on same XCD

// scatter LDS: hist/pref/gbase/rank (4*196*4=3136) + sortedP 32K
#define SMEM_BYTES (3136 + SC_E * 4)

// ---------------------------------------------------------------------------
// Fused proj + scatter. hW stored in BF16: 3.2 MB fits a 4 MiB XCD L2 —
// r11's fp32 hW (6.4 MB) thrashed L2 and every agg gather went to L3/HBM
// (90 MB FETCH on agg).
// ---------------------------------------------------------------------------
__global__ __launch_bounds__(256) void proj_scatter_kernel(
    const float* __restrict__ h, const float* __restrict__ W,
    const float* __restrict__ a_l, const float* __restrict__ a_r,
    const int* __restrict__ src, const int* __restrict__ dst,
    __hip_bfloat16* __restrict__ hWbf, float* __restrict__ el,
    float* __restrict__ er, int* __restrict__ cursor,
    uint32_t* __restrict__ payload, int N, int E, int scatBlocks) {
  __shared__ __align__(16) uint8_t smem[SMEM_BYTES];
  int t = threadIdx.x;

  if ((int)blockIdx.x < scatBlocks) {
    // ---------------- scatter branch ----------------
    int* hist = (int*)smem;          // NBS
    int* pref = hist + NBS;
    int* gbase = pref + NBS;
    int* rank = gbase + NBS;
    uint32_t* sortedP = (uint32_t*)(smem + 3136);  // SC_E

    int start = blockIdx.x * SC_E;
    int end = min(E, start + SC_E);
    int cnt = end - start;

    if (t < NBS) { hist[t] = 0; rank[t] = 0; }
    __syncthreads();

    const int4* d4 = (const int4*)(dst + start);
    int n4 = cnt >> 2;
    for (int i = t; i < n4; i += 256) {
      int4 d = d4[i];
      atomicAdd(&hist[d.x >> SB_BITS], 1);
      atomicAdd(&hist[d.y >> SB_BITS], 1);
      atomicAdd(&hist[d.z >> SB_BITS], 1);
      atomicAdd(&hist[d.w >> SB_BITS], 1);
    }
    for (int i = start + (n4 << 2) + t; i < end; i += 256)
      atomicAdd(&hist[dst[i] >> SB_BITS], 1);
    __syncthreads();

    if (t < NBS) {  // parallel O(n) exclusive prefix + range reservation
      int s = 0;
      for (int j = 0; j < t; ++j) s += hist[j];
      pref[t] = s;
      int c = hist[t];
      gbase[t] = c ? atomicAdd(&cursor[t * 16], c) : 0;  // cursor pre-zeroed
    }
    __syncthreads();

    const int4* s4 = (const int4*)(src + start);
    for (int i = t; i < n4; i += 256) {
      int4 d = d4[i];
      int4 s = s4[i];
#pragma unroll
      for (int j = 0; j < 4; ++j) {
        int dd = j == 0 ? d.x : j == 1 ? d.y : j == 2 ? d.z : d.w;
        int ss = j == 0 ? s.x : j == 1 ? s.y : j == 2 ? s.z : s.w;
        int b = dd >> SB_BITS;
        int r = atomicAdd(&rank[b], 1);
        sortedP[pref[b] + r] =
            ((uint32_t)ss << SB_BITS) | (uint32_t)(dd & (SB_NODES - 1));
      }
    }
    for (int i = start + (n4 << 2) + t; i < end; i += 256) {
      int dd = dst[i];
      int b = dd >> SB_BITS;
      int r = atomicAdd(&rank[b], 1);
      sortedP[pref[b] + r] =
          ((uint32_t)src[i] << SB_BITS) | (uint32_t)(dd & (SB_NODES - 1));
    }
    __syncthreads();

    // write-out: per-bucket run copy (wave per bucket)
    int wv = t >> 6, ln = t & 63;
    for (int b = wv; b < NBS; b += 4) {
      int c = hist[b];
      int p0 = pref[b];
      size_t g0 = (size_t)b * CAP_SB + gbase[b];
      for (int j = ln; j < c; j += 64)
        if (gbase[b] + j < CAP_SB) payload[g0 + j] = sortedP[p0 + j];
    }
  } else {
    // ---------------- projection branch ----------------
    float* Ws = (float*)smem;  // OUT_F * W_LD = 8448 B < SMEM_BYTES
    for (int i = t; i < OUT_F * IN_F; i += 256)
      Ws[(i >> 7) * W_LD + (i & (IN_F - 1))] = W[i];
    __syncthreads();

    int gid = ((int)blockIdx.x - scatBlocks) * 256 + t;
    int node = gid >> 4;
    int feat = gid & 15;
    if (node >= N) return;

    const float4* hrow = (const float4*)(h + (size_t)node * IN_F);
    const float4* wrow = (const float4*)(&Ws[feat * W_LD]);
    float acc = 0.f;
#pragma unroll
    for (int k = 0; k < IN_F / 4; ++k) {
      float4 hv = hrow[k];
      float4 wv = wrow[k];
      acc += hv.x * wv.x + hv.y * wv.y + hv.z * wv.z + hv.w * wv.w;
    }
    hWbf[node * OUT_F + feat] = __float2bfloat16(acc);

    float vl = acc * a_l[feat];
    float vr = acc * a_r[feat];
#pragma unroll
    for (int off = 8; off; off >>= 1) {
      vl += __shfl_down(vl, off, 16);
      vr += __shfl_down(vr, off, 16);
    }
    if (feat == 0) {
      el[node] = vl;
      er[node] = vr;
    }
  }
}

// ---------------------------------------------------------------------------
// Fused sort+aggregate, single global payload scan per quad (r11 scanned
// twice). Pass 1: uint4 scan + ballot-compact into kept[] (aliases exS).
// Pass 2-4: hist/prefix/place from LDS. Pass 5: exp once per edge -> exS[]
// (kept[] dead by then). Pass 6: r8's measured-good 16-lane-group CSR loop,
// gathering BF16 hW rows (32 B, L2-resident).
// ---------------------------------------------------------------------------
__global__ __launch_bounds__(512) void agg_kernel(
    const uint32_t* __restrict__ payload, const int* __restrict__ cursor,
    const __hip_bfloat16* __restrict__ hWbf, const float* __restrict__ el,
    const float* __restrict__ er, float* __restrict__ out, int N) {
  __shared__ uint32_t sorted[LCAP];  // 18 KB
  __shared__ float exS[LCAP];        // 18 KB (aliased as kept[] pass 1-4)
  __shared__ int hist[TILE_NODES];
  __shared__ int pref[TILE_NODES];
  __shared__ int rank[TILE_NODES];
  __shared__ int kcnt;
  uint32_t* kept = (uint32_t*)exS;

  int t = threadIdx.x;
  int sb = blockIdx.x % SB_SPACING;
  uint32_t quad = blockIdx.x / SB_SPACING;
  if (sb >= NBS) return;
  size_t base = (size_t)sb * CAP_SB;
  int cnt = min(cursor[sb * 16], CAP_SB);

  if (t < TILE_NODES) { hist[t] = 0; rank[t] = 0; }
  if (t == 0) kcnt = 0;
  __syncthreads();

  // pass 1: single global scan, ballot-compact
  const uint4* pay4 = (const uint4*)(payload + base);  // CAP_SB%4==0
  int n4 = (cnt + 3) >> 2;
  int lane = t & 63;
  for (int i = t; i < n4; i += 512) {
    uint4 v = pay4[i];
    int i0 = i << 2;
#pragma unroll
    for (int j = 0; j < 4; ++j) {
      uint32_t p = j == 0 ? v.x : j == 1 ? v.y : j == 2 ? v.z : v.w;
      bool keep = (i0 + j < cnt) && (((p >> 7) & 3u) == quad);
      unsigned long long m = __ballot(keep);
      if (m) {
        int leader = (int)(__ffsll((long long)m) - 1);
        int bbase = 0;
        if (lane == leader) bbase = atomicAdd(&kcnt, (int)__popcll(m));
        bbase = __shfl(bbase, leader);
        if (keep)
          kept[bbase + (int)__popcll(m & ((1ull << lane) - 1))] = p;
      }
    }
  }
  __syncthreads();
  int K = min(kcnt, LCAP);

  // pass 2: hist from LDS
  for (int i = t; i < K; i += 512)
    atomicAdd(&hist[kept[i] & (TILE_NODES - 1)], 1);
  __syncthreads();

  // pass 3: prefix
  if (t < TILE_NODES) {
    int s = 0;
    for (int j = 0; j < t; ++j) s += hist[j];
    pref[t] = s;
  }
  __syncthreads();

  // pass 4: place kept -> sorted
  for (int i = t; i < K; i += 512) {
    uint32_t p = kept[i];
    int dl = (int)(p & (TILE_NODES - 1));
    int r = atomicAdd(&rank[dl], 1);
    sorted[pref[dl] + r] = p;
  }
  __syncthreads();

  // pass 5: exp once per edge (overwrites kept — dead after pass 4)
  int node0 = sb * SB_NODES + (int)quad * TILE_NODES;
  for (int i = t; i < K; i += 512) {
    uint32_t p = sorted[i];
    int s = (int)(p >> SB_BITS);
    float x = el[s] + er[node0 + (int)(p & (TILE_NODES - 1))];
    x = x > 0.f ? x : NEG_SLOPE * x;
    exS[i] = __expf(x);
  }
  __syncthreads();

  // pass 6: 16-lane-group register CSR aggregation, bf16 gather
  int g = t >> 4;  // 32 groups of 16 lanes
  int f = t & 15;
  for (int dl = g; dl < TILE_NODES; dl += 32) {
    int node = node0 + dl;
    if (node >= N) break;
    int k = pref[dl];
    int kend = k + hist[dl];
    float acc = 0.f;
    float es = 0.f;
#pragma unroll 4
    for (; k < kend; ++k) {
      float ex = exS[k];
      acc += ex * __bfloat162float(hWbf[(int)(sorted[k] >> SB_BITS) * OUT_F + f]);
      es += ex;
    }
    out[(size_t)node * OUT_F + f] = acc / fmaxf(es, 1e-16f);
  }
}

extern "C" void kernel_launch(void* const* d_in, const int* in_sizes, int n_in,
                              void* d_out, int out_size, void* d_ws, size_t ws_size,
                              hipStream_t stream) {
  const float* h   = (const float*)d_in[0];
  const int*   src = (const int*)d_in[1];
  const int*   dst = (const int*)d_in[2];
  const float* W   = (const float*)d_in[3];
  const float* a_l = (const float*)d_in[4];
  const float* a_r = (const float*)d_in[5];
  float* out = (float*)d_out;

  const int N = in_sizes[0] / IN_F;
  const int E = in_sizes[1];
  const int scatBlocks = (E + SC_E - 1) / SC_E;      // 391
  const int projBlocks = (N * OUT_F + 255) / 256;    // 6250

  // ws: hWbf (bf16) | el | er | cursor | payload
  __hip_bfloat16* hWbf = (__hip_bfloat16*)d_ws;        // N*16 bf16 = 3.2 MB
  float* el = (float*)(hWbf + (size_t)N * OUT_F);      // N
  float* er = el + N;                                  // N
  int* cursor = (int*)(er + N);                        // NBS*16 (line-strided)
  uint32_t* payload = (uint32_t*)(cursor + (size_t)NBS * 16);  // NBS*CAP_SB

  hipMemsetAsync(cursor, 0, (size_t)NBS * 16 * sizeof(int), stream);

  proj_scatter_kernel<<<scatBlocks + projBlocks, 256, 0, stream>>>(
      h, W, a_l, a_r, src, dst, hWbf, el, er, cursor, payload, N, E, scatBlocks);

  agg_kernel<<<SB_SPACING * 4, 512, 0, stream>>>(payload, cursor, hWbf, el, er,
                                                 out, N);
}

// Round 13
// 184.445 us; speedup vs baseline: 2.8820x; 1.0679x over previous
//
#include <hip/hip_runtime.h>
#include <hip/hip_bf16.h>
#include <stdint.h>

#define IN_F 128
#define OUT_F 16
#define NEG_SLOPE 0.2f
#define SB_BITS 9               // super-bucket = 512 nodes (scatter granularity)
#define SB_NODES 512
#define NBS 196                 // ceil(100000/512)
#define CAP_SB 17408            // mean 16366, sigma ~127 -> +8 sigma
#define TILE_NODES 128          // agg output tile (quad of an SB)
#define LCAP 4608               // per-quad capacity (mean 4092, +8 sigma)
#define SC_E 8192               // edges per scatter block
#define SB_SPACING 200          // 200%8==0 -> all 4 quads of an SB on same XCD

// scatter LDS: hist/pref/gbase/rank (4*196*4=3136) + sortedP 32K
#define SMEM_BYTES (3136 + SC_E * 4)

// ---------------------------------------------------------------------------
// Fused proj + scatter. Projection is ONE THREAD PER NODE (r12 used 16
// threads/node, each redundantly reading the full 512 B h-row -> ~800 MB
// through L1). Thread streams its row once, acc[16] in registers, W chunks
// read wave-uniform from LDS (broadcast, conflict-free). hW stored BF16
// (3.2 MB, fits 4 MiB XCD L2 for agg's gathers).
// ---------------------------------------------------------------------------
__global__ __launch_bounds__(256) void proj_scatter_kernel(
    const float* __restrict__ h, const float* __restrict__ W,
    const float* __restrict__ a_l, const float* __restrict__ a_r,
    const int* __restrict__ src, const int* __restrict__ dst,
    __hip_bfloat16* __restrict__ hWbf, float* __restrict__ el,
    float* __restrict__ er, int* __restrict__ cursor,
    uint32_t* __restrict__ payload, int N, int E, int scatBlocks) {
  __shared__ __align__(16) uint8_t smem[SMEM_BYTES];
  int t = threadIdx.x;

  if ((int)blockIdx.x < scatBlocks) {
    // ---------------- scatter branch (unchanged from r12) ----------------
    int* hist = (int*)smem;          // NBS
    int* pref = hist + NBS;
    int* gbase = pref + NBS;
    int* rank = gbase + NBS;
    uint32_t* sortedP = (uint32_t*)(smem + 3136);  // SC_E

    int start = blockIdx.x * SC_E;
    int end = min(E, start + SC_E);
    int cnt = end - start;

    if (t < NBS) { hist[t] = 0; rank[t] = 0; }
    __syncthreads();

    const int4* d4 = (const int4*)(dst + start);
    int n4 = cnt >> 2;
    for (int i = t; i < n4; i += 256) {
      int4 d = d4[i];
      atomicAdd(&hist[d.x >> SB_BITS], 1);
      atomicAdd(&hist[d.y >> SB_BITS], 1);
      atomicAdd(&hist[d.z >> SB_BITS], 1);
      atomicAdd(&hist[d.w >> SB_BITS], 1);
    }
    for (int i = start + (n4 << 2) + t; i < end; i += 256)
      atomicAdd(&hist[dst[i] >> SB_BITS], 1);
    __syncthreads();

    if (t < NBS) {  // parallel O(n) exclusive prefix + range reservation
      int s = 0;
      for (int j = 0; j < t; ++j) s += hist[j];
      pref[t] = s;
      int c = hist[t];
      gbase[t] = c ? atomicAdd(&cursor[t * 16], c) : 0;  // cursor pre-zeroed
    }
    __syncthreads();

    const int4* s4 = (const int4*)(src + start);
    for (int i = t; i < n4; i += 256) {
      int4 d = d4[i];
      int4 s = s4[i];
#pragma unroll
      for (int j = 0; j < 4; ++j) {
        int dd = j == 0 ? d.x : j == 1 ? d.y : j == 2 ? d.z : d.w;
        int ss = j == 0 ? s.x : j == 1 ? s.y : j == 2 ? s.z : s.w;
        int b = dd >> SB_BITS;
        int r = atomicAdd(&rank[b], 1);
        sortedP[pref[b] + r] =
            ((uint32_t)ss << SB_BITS) | (uint32_t)(dd & (SB_NODES - 1));
      }
    }
    for (int i = start + (n4 << 2) + t; i < end; i += 256) {
      int dd = dst[i];
      int b = dd >> SB_BITS;
      int r = atomicAdd(&rank[b], 1);
      sortedP[pref[b] + r] =
          ((uint32_t)src[i] << SB_BITS) | (uint32_t)(dd & (SB_NODES - 1));
    }
    __syncthreads();

    // write-out: per-bucket run copy (wave per bucket)
    int wv = t >> 6, ln = t & 63;
    for (int b = wv; b < NBS; b += 4) {
      int c = hist[b];
      int p0 = pref[b];
      size_t g0 = (size_t)b * CAP_SB + gbase[b];
      for (int j = ln; j < c; j += 64)
        if (gbase[b] + j < CAP_SB) payload[g0 + j] = sortedP[p0 + j];
    }
  } else {
    // ---------------- projection branch: one thread per node ----------------
    float* Ws = (float*)smem;  // 16*128 floats = 8 KB (reads are wave-uniform
                               // broadcast -> no bank-conflict concern)
    for (int i = t; i < OUT_F * IN_F; i += 256) Ws[i] = W[i];
    __syncthreads();

    int node = ((int)blockIdx.x - scatBlocks) * 256 + t;
    if (node >= N) return;

    const float4* hrow = (const float4*)(h + (size_t)node * IN_F);
    float acc[OUT_F];
#pragma unroll
    for (int f = 0; f < OUT_F; ++f) acc[f] = 0.f;

#pragma unroll 4
    for (int k = 0; k < IN_F / 4; ++k) {
      float4 hv = hrow[k];
#pragma unroll
      for (int f = 0; f < OUT_F; ++f) {
        float4 wv = ((const float4*)(Ws + f * IN_F))[k];  // uniform -> bcast
        acc[f] += hv.x * wv.x + hv.y * wv.y + hv.z * wv.z + hv.w * wv.w;
      }
    }

    // pack 16 bf16 and store as two uint4 (32 B/node)
    union {
      unsigned short us[OUT_F];
      uint4 q[2];
    } pk;
#pragma unroll
    for (int f = 0; f < OUT_F; ++f) {
      __hip_bfloat16 b = __float2bfloat16(acc[f]);
      pk.us[f] = *reinterpret_cast<unsigned short*>(&b);
    }
    uint4* dstq = (uint4*)(hWbf + (size_t)node * OUT_F);
    dstq[0] = pk.q[0];
    dstq[1] = pk.q[1];

    float vl = 0.f, vr = 0.f;
#pragma unroll
    for (int f = 0; f < OUT_F; ++f) {
      vl += acc[f] * a_l[f];
      vr += acc[f] * a_r[f];
    }
    el[node] = vl;
    er[node] = vr;
  }
}

// ---------------------------------------------------------------------------
// Fused sort+aggregate (unchanged from r12 — measured good: out of top-5).
// Single global payload scan per quad -> ballot-compact -> LDS hist/prefix/
// place -> exp once per edge -> 16-lane-group CSR loop on L2-resident bf16 hW.
// ---------------------------------------------------------------------------
__global__ __launch_bounds__(512) void agg_kernel(
    const uint32_t* __restrict__ payload, const int* __restrict__ cursor,
    const __hip_bfloat16* __restrict__ hWbf, const float* __restrict__ el,
    const float* __restrict__ er, float* __restrict__ out, int N) {
  __shared__ uint32_t sorted[LCAP];  // 18 KB
  __shared__ float exS[LCAP];        // 18 KB (aliased as kept[] pass 1-4)
  __shared__ int hist[TILE_NODES];
  __shared__ int pref[TILE_NODES];
  __shared__ int rank[TILE_NODES];
  __shared__ int kcnt;
  uint32_t* kept = (uint32_t*)exS;

  int t = threadIdx.x;
  int sb = blockIdx.x % SB_SPACING;
  uint32_t quad = blockIdx.x / SB_SPACING;
  if (sb >= NBS) return;
  size_t base = (size_t)sb * CAP_SB;
  int cnt = min(cursor[sb * 16], CAP_SB);

  if (t < TILE_NODES) { hist[t] = 0; rank[t] = 0; }
  if (t == 0) kcnt = 0;
  __syncthreads();

  // pass 1: single global scan, ballot-compact
  const uint4* pay4 = (const uint4*)(payload + base);  // CAP_SB%4==0
  int n4 = (cnt + 3) >> 2;
  int lane = t & 63;
  for (int i = t; i < n4; i += 512) {
    uint4 v = pay4[i];
    int i0 = i << 2;
#pragma unroll
    for (int j = 0; j < 4; ++j) {
      uint32_t p = j == 0 ? v.x : j == 1 ? v.y : j == 2 ? v.z : v.w;
      bool keep = (i0 + j < cnt) && (((p >> 7) & 3u) == quad);
      unsigned long long m = __ballot(keep);
      if (m) {
        int leader = (int)(__ffsll((long long)m) - 1);
        int bbase = 0;
        if (lane == leader) bbase = atomicAdd(&kcnt, (int)__popcll(m));
        bbase = __shfl(bbase, leader);
        if (keep)
          kept[bbase + (int)__popcll(m & ((1ull << lane) - 1))] = p;
      }
    }
  }
  __syncthreads();
  int K = min(kcnt, LCAP);

  // pass 2: hist from LDS
  for (int i = t; i < K; i += 512)
    atomicAdd(&hist[kept[i] & (TILE_NODES - 1)], 1);
  __syncthreads();

  // pass 3: prefix
  if (t < TILE_NODES) {
    int s = 0;
    for (int j = 0; j < t; ++j) s += hist[j];
    pref[t] = s;
  }
  __syncthreads();

  // pass 4: place kept -> sorted
  for (int i = t; i < K; i += 512) {
    uint32_t p = kept[i];
    int dl = (int)(p & (TILE_NODES - 1));
    int r = atomicAdd(&rank[dl], 1);
    sorted[pref[dl] + r] = p;
  }
  __syncthreads();

  // pass 5: exp once per edge (overwrites kept — dead after pass 4)
  int node0 = sb * SB_NODES + (int)quad * TILE_NODES;
  for (int i = t; i < K; i += 512) {
    uint32_t p = sorted[i];
    int s = (int)(p >> SB_BITS);
    float x = el[s] + er[node0 + (int)(p & (TILE_NODES - 1))];
    x = x > 0.f ? x : NEG_SLOPE * x;
    exS[i] = __expf(x);
  }
  __syncthreads();

  // pass 6: 16-lane-group register CSR aggregation, bf16 gather
  int g = t >> 4;  // 32 groups of 16 lanes
  int f = t & 15;
  for (int dl = g; dl < TILE_NODES; dl += 32) {
    int node = node0 + dl;
    if (node >= N) break;
    int k = pref[dl];
    int kend = k + hist[dl];
    float acc = 0.f;
    float es = 0.f;
#pragma unroll 4
    for (; k < kend; ++k) {
      float ex = exS[k];
      acc += ex * __bfloat162float(hWbf[(int)(sorted[k] >> SB_BITS) * OUT_F + f]);
      es += ex;
    }
    out[(size_t)node * OUT_F + f] = acc / fmaxf(es, 1e-16f);
  }
}

extern "C" void kernel_launch(void* const* d_in, const int* in_sizes, int n_in,
                              void* d_out, int out_size, void* d_ws, size_t ws_size,
                              hipStream_t stream) {
  const float* h   = (const float*)d_in[0];
  const int*   src = (const int*)d_in[1];
  const int*   dst = (const int*)d_in[2];
  const float* W   = (const float*)d_in[3];
  const float* a_l = (const float*)d_in[4];
  const float* a_r = (const float*)d_in[5];
  float* out = (float*)d_out;

  const int N = in_sizes[0] / IN_F;
  const int E = in_sizes[1];
  const int scatBlocks = (E + SC_E - 1) / SC_E;      // 391
  const int projBlocks = (N + 255) / 256;            // 391 (1 thread/node)

  // ws: hWbf (bf16) | el | er | cursor | payload
  __hip_bfloat16* hWbf = (__hip_bfloat16*)d_ws;        // N*16 bf16 = 3.2 MB
  float* el = (float*)(hWbf + (size_t)N * OUT_F);      // N
  float* er = el + N;                                  // N
  int* cursor = (int*)(er + N);                        // NBS*16 (line-strided)
  uint32_t* payload = (uint32_t*)(cursor + (size_t)NBS * 16);  // NBS*CAP_SB

  hipMemsetAsync(cursor, 0, (size_t)NBS * 16 * sizeof(int), stream);

  proj_scatter_kernel<<<scatBlocks + projBlocks, 256, 0, stream>>>(
      h, W, a_l, a_r, src, dst, hWbf, el, er, cursor, payload, N, E, scatBlocks);

  agg_kernel<<<SB_SPACING * 4, 512, 0, stream>>>(payload, cursor, hWbf, el, er,
                                                 out, N);
}